// Round 10
// baseline (557.459 us; speedup 1.0000x reference)
//
#include <hip/hip_runtime.h>
#include <math.h>

#define EMB 64

typedef float f32x4 __attribute__((ext_vector_type(4)));

// ---------- CSR build ----------

// one pass: count AND per-edge rank (rank = atomicAdd return). 1 edge/thread.
__global__ void count_rank_k(const int* __restrict__ el, int* __restrict__ cnt,
                             int* __restrict__ rank, int n) {
    int i = blockIdx.x * blockDim.x + threadIdx.x;
    if (i < n) rank[i] = atomicAdd(cnt + el[i], 1);
}

__global__ void block_sum_k(const int* __restrict__ cnt, int* __restrict__ part, int n) {
    __shared__ int s[256];
    int i = blockIdx.x * 256 + threadIdx.x;
    s[threadIdx.x] = (i < n) ? cnt[i] : 0;
    __syncthreads();
    for (int off = 128; off > 0; off >>= 1) {
        if (threadIdx.x < off) s[threadIdx.x] += s[threadIdx.x + off];
        __syncthreads();
    }
    if (threadIdx.x == 0) part[blockIdx.x] = s[0];
}

// single-block exclusive scan of nb (<=4096) partials, 1024 threads
__global__ void scan_part_k(int* __restrict__ part, int nb) {
    __shared__ int s[4096];
    for (int i = threadIdx.x; i < 4096; i += 1024) s[i] = (i < nb) ? part[i] : 0;
    __syncthreads();
    for (int off = 1; off < 4096; off <<= 1) {
        int vals[4];
        #pragma unroll
        for (int j = 0; j < 4; ++j) {
            int i = threadIdx.x + j * 1024;
            vals[j] = (i >= off) ? s[i - off] : 0;
        }
        __syncthreads();
        #pragma unroll
        for (int j = 0; j < 4; ++j) {
            int i = threadIdx.x + j * 1024;
            s[i] += vals[j];
        }
        __syncthreads();
    }
    for (int i = threadIdx.x; i < nb; i += 1024) part[i] = (i == 0) ? 0 : s[i - 1];
}

// writes offs[i] (for fill) and meta[i]=(offs,cnt) (for gather)
__global__ void scan_meta_k(const int* __restrict__ cnt, const int* __restrict__ part,
                            int* __restrict__ offs, int2* __restrict__ meta, int n) {
    __shared__ int s[256];
    int i = blockIdx.x * 256 + threadIdx.x;
    int v = (i < n) ? cnt[i] : 0;
    s[threadIdx.x] = v;
    __syncthreads();
    for (int off = 1; off < 256; off <<= 1) {
        int t = (threadIdx.x >= (unsigned)off) ? s[threadIdx.x - off] : 0;
        __syncthreads();
        s[threadIdx.x] += t;
        __syncthreads();
    }
    if (i < n) {
        int excl = s[threadIdx.x] - v + part[blockIdx.x];
        offs[i] = excl;
        int2 m; m.x = excl; m.y = v;
        meta[i] = m;
    }
}

// atomic-free fill using precomputed ranks; 1 edge/thread
__global__ void fill_csr_k(const int* __restrict__ el, const int* __restrict__ rank,
                           const int* __restrict__ offs, int* __restrict__ csr, int n) {
    int i = blockIdx.x * blockDim.x + threadIdx.x;
    if (i < n) csr[offs[el[i]] + rank[i]] = i;
}

// ---------- gather: 8 lanes per location (8 locs/wave), 8 rows in flight ----------
// vs round 9 (16 lanes/loc): doubles independent dependent-chains per wave and
// doubles noise bytes-in-flight per wave (8 KB -> 16 KB) to attack latency.

__global__ __launch_bounds__(256)
void gather_k(const float* __restrict__ loc_emb, const float* __restrict__ noise,
              const int2* __restrict__ meta, const int* __restrict__ csr,
              float* __restrict__ out, float sigma, int n_locs) {
    int gid = blockIdx.x * blockDim.x + threadIdx.x;
    int loc = gid >> 3;
    if (loc >= n_locs) return;
    int q = gid & 7;                    // lane's 32B chunk of the 256B row
    int2 m = meta[loc];                 // one 8B load: (offset, count)
    int st = m.x, c = m.y;
    long long ebase = ((long long)loc << 6) + (q << 3);
    const f32x4* bp = reinterpret_cast<const f32x4*>(loc_emb + ebase);
    f32x4 b0 = __builtin_nontemporal_load(bp);
    f32x4 b1 = __builtin_nontemporal_load(bp + 1);
    f32x4 acc0 = (f32x4)(0.f), acc1 = (f32x4)(0.f);
    for (int i = 0; i < c; i += 8) {
        int r = c - i;          // >= 1
        int bofs = st + i;
        int e[8];
        #pragma unroll
        for (int j = 0; j < 8; ++j)
            e[j] = csr[bofs + (j < r ? j : r - 1)];   // clamped, in-bounds
        f32x4 v0[8], v1[8];
        #pragma unroll
        for (int j = 0; j < 8; ++j) {
            const f32x4* p = reinterpret_cast<const f32x4*>(noise + ((long long)e[j] << 6) + (q << 3));
            v0[j] = p[0];
            v1[j] = p[1];       // 16 independent 16B loads in flight per lane
        }
        #pragma unroll
        for (int j = 0; j < 8; ++j)
            if (j < r) { acc0 += v0[j]; acc1 += v1[j]; }
    }
    float s = (c > 0) ? sigma / (float)c : 0.f;
    f32x4 o0 = b0 + s * acc0;
    f32x4 o1 = b1 + s * acc1;
    f32x4* op = reinterpret_cast<f32x4*>(out + ebase);
    __builtin_nontemporal_store(o0, op);
    __builtin_nontemporal_store(o1, op + 1);
}

extern "C" void kernel_launch(void* const* d_in, const int* in_sizes, int n_in,
                              void* d_out, int out_size, void* d_ws, size_t ws_size,
                              hipStream_t stream) {
    const float* loc_emb = (const float*)d_in[0];
    const float* noise   = (const float*)d_in[1];
    const int*   el      = (const int*)d_in[2];
    float* out = (float*)d_out;

    int n_locs  = in_sizes[0] / EMB;
    int n_edges = in_sizes[2];

    // workspace layout (all 16B-aligned)
    char* w = (char*)d_ws;
    int*  cnt  = (int*)w;                 w += (size_t)n_locs * sizeof(int);
    int*  part = (int*)w;                 w += 4096 * sizeof(int);
    int*  offs = (int*)w;                 w += (size_t)n_locs * sizeof(int);
    int2* meta = (int2*)w;                w += (size_t)n_locs * sizeof(int2);
    int*  rank = (int*)w;                 w += (size_t)n_edges * sizeof(int);
    int*  csr  = (int*)w;

    int nb = (n_locs + 255) / 256;

    (void)hipMemsetAsync(cnt, 0, (size_t)n_locs * sizeof(int), stream);

    count_rank_k<<<(n_edges + 255) / 256, 256, 0, stream>>>(el, cnt, rank, n_edges);
    block_sum_k<<<nb, 256, 0, stream>>>(cnt, part, n_locs);
    scan_part_k<<<1, 1024, 0, stream>>>(part, nb);
    scan_meta_k<<<nb, 256, 0, stream>>>(cnt, part, offs, meta, n_locs);
    fill_csr_k<<<(n_edges + 255) / 256, 256, 0, stream>>>(el, rank, offs, csr, n_edges);

    double sigma = 1.0 * sqrt(2.0 * log(1.25 / 1e-5)) / 1.0;
    long long total = (long long)n_locs * 8;      // 8 lanes per loc
    int blocks = (int)((total + 255) / 256);
    gather_k<<<blocks, 256, 0, stream>>>(loc_emb, noise, meta, csr, out,
                                         (float)sigma, n_locs);
}

// Round 11
// 537.133 us; speedup vs baseline: 1.0378x; 1.0378x over previous
//
#include <hip/hip_runtime.h>
#include <math.h>

#define EMB 64

typedef float f32x4 __attribute__((ext_vector_type(4)));

// ---------- CSR build ----------

// one pass: count AND per-edge rank (rank = atomicAdd return). 1 edge/thread.
__global__ void count_rank_k(const int* __restrict__ el, int* __restrict__ cnt,
                             int* __restrict__ rank, int n) {
    int i = blockIdx.x * blockDim.x + threadIdx.x;
    if (i < n) rank[i] = atomicAdd(cnt + el[i], 1);
}

__global__ void block_sum_k(const int* __restrict__ cnt, int* __restrict__ part, int n) {
    __shared__ int s[256];
    int i = blockIdx.x * 256 + threadIdx.x;
    s[threadIdx.x] = (i < n) ? cnt[i] : 0;
    __syncthreads();
    for (int off = 128; off > 0; off >>= 1) {
        if (threadIdx.x < off) s[threadIdx.x] += s[threadIdx.x + off];
        __syncthreads();
    }
    if (threadIdx.x == 0) part[blockIdx.x] = s[0];
}

// single-block exclusive scan of nb (<=4096) partials, 1024 threads
__global__ void scan_part_k(int* __restrict__ part, int nb) {
    __shared__ int s[4096];
    for (int i = threadIdx.x; i < 4096; i += 1024) s[i] = (i < nb) ? part[i] : 0;
    __syncthreads();
    for (int off = 1; off < 4096; off <<= 1) {
        int vals[4];
        #pragma unroll
        for (int j = 0; j < 4; ++j) {
            int i = threadIdx.x + j * 1024;
            vals[j] = (i >= off) ? s[i - off] : 0;
        }
        __syncthreads();
        #pragma unroll
        for (int j = 0; j < 4; ++j) {
            int i = threadIdx.x + j * 1024;
            s[i] += vals[j];
        }
        __syncthreads();
    }
    for (int i = threadIdx.x; i < nb; i += 1024) part[i] = (i == 0) ? 0 : s[i - 1];
}

// writes offs[i] (for fill) and meta[i]=(offs,cnt) (for gather)
__global__ void scan_meta_k(const int* __restrict__ cnt, const int* __restrict__ part,
                            int* __restrict__ offs, int2* __restrict__ meta, int n) {
    __shared__ int s[256];
    int i = blockIdx.x * 256 + threadIdx.x;
    int v = (i < n) ? cnt[i] : 0;
    s[threadIdx.x] = v;
    __syncthreads();
    for (int off = 1; off < 256; off <<= 1) {
        int t = (threadIdx.x >= (unsigned)off) ? s[threadIdx.x - off] : 0;
        __syncthreads();
        s[threadIdx.x] += t;
        __syncthreads();
    }
    if (i < n) {
        int excl = s[threadIdx.x] - v + part[blockIdx.x];
        offs[i] = excl;
        int2 m; m.x = excl; m.y = v;
        meta[i] = m;
    }
}

// atomic-free fill using precomputed ranks; 1 edge/thread
__global__ void fill_csr_k(const int* __restrict__ el, const int* __restrict__ rank,
                           const int* __restrict__ offs, int* __restrict__ csr, int n) {
    int i = blockIdx.x * blockDim.x + threadIdx.x;
    if (i < n) csr[offs[el[i]] + rank[i]] = i;
}

// ---------- gather: 16 lanes per location, float4 per lane, 8 rows in flight ----------

__device__ __forceinline__ f32x4 ld_row(const float* noise, int e, int q) {
    // plain (cached) load: clamped duplicate tail loads hit L1, no extra DRAM traffic
    return *(reinterpret_cast<const f32x4*>(noise + ((long long)e << 6)) + q);
}

__global__ __launch_bounds__(256, 8)
void gather_k(const float* __restrict__ loc_emb, const float* __restrict__ noise,
              const int2* __restrict__ meta, const int* __restrict__ csr,
              float* __restrict__ out, float sigma, int n_locs) {
    int gid = blockIdx.x * blockDim.x + threadIdx.x;
    int loc = gid >> 4;
    if (loc >= n_locs) return;
    int q = gid & 15;
    int2 m = meta[loc];               // one 8B load: (offset, count)
    int st = m.x, c = m.y;
    // hoist the independent emb load so it overlaps the meta->csr->noise chain
    const f32x4* bp = reinterpret_cast<const f32x4*>(loc_emb + ((long long)loc << 6)) + q;
    f32x4 b = __builtin_nontemporal_load(bp);
    f32x4 acc = (f32x4)(0.f);
    for (int i = 0; i < c; i += 8) {
        int r = c - i;          // >= 1
        int b0 = st + i;
        int e[8];
        #pragma unroll
        for (int j = 0; j < 8; ++j)
            e[j] = csr[b0 + (j < r ? j : r - 1)];   // clamped, in-bounds (broadcast dups free)
        f32x4 v[8];
        #pragma unroll
        for (int j = 0; j < 8; ++j)
            v[j] = ld_row(noise, e[j], q);          // 8 independent 256B rows in flight
        #pragma unroll
        for (int j = 0; j < 8; ++j)
            if (j < r) acc += v[j];
    }
    float s = (c > 0) ? sigma / (float)c : 0.f;
    f32x4 o = b + s * acc;
    f32x4* op = reinterpret_cast<f32x4*>(out + ((long long)loc << 6)) + q;
    __builtin_nontemporal_store(o, op);
}

extern "C" void kernel_launch(void* const* d_in, const int* in_sizes, int n_in,
                              void* d_out, int out_size, void* d_ws, size_t ws_size,
                              hipStream_t stream) {
    const float* loc_emb = (const float*)d_in[0];
    const float* noise   = (const float*)d_in[1];
    const int*   el      = (const int*)d_in[2];
    float* out = (float*)d_out;

    int n_locs  = in_sizes[0] / EMB;
    int n_edges = in_sizes[2];

    // workspace layout (all 16B-aligned)
    char* w = (char*)d_ws;
    int*  cnt  = (int*)w;                 w += (size_t)n_locs * sizeof(int);
    int*  part = (int*)w;                 w += 4096 * sizeof(int);
    int*  offs = (int*)w;                 w += (size_t)n_locs * sizeof(int);
    int2* meta = (int2*)w;                w += (size_t)n_locs * sizeof(int2);
    int*  rank = (int*)w;                 w += (size_t)n_edges * sizeof(int);
    int*  csr  = (int*)w;

    int nb = (n_locs + 255) / 256;

    (void)hipMemsetAsync(cnt, 0, (size_t)n_locs * sizeof(int), stream);

    count_rank_k<<<(n_edges + 255) / 256, 256, 0, stream>>>(el, cnt, rank, n_edges);
    block_sum_k<<<nb, 256, 0, stream>>>(cnt, part, n_locs);
    scan_part_k<<<1, 1024, 0, stream>>>(part, nb);
    scan_meta_k<<<nb, 256, 0, stream>>>(cnt, part, offs, meta, n_locs);
    fill_csr_k<<<(n_edges + 255) / 256, 256, 0, stream>>>(el, rank, offs, csr, n_edges);

    double sigma = 1.0 * sqrt(2.0 * log(1.25 / 1e-5)) / 1.0;
    long long total = (long long)n_locs * 16;
    int blocks = (int)((total + 255) / 256);
    gather_k<<<blocks, 256, 0, stream>>>(loc_emb, noise, meta, csr, out,
                                         (float)sigma, n_locs);
}